// Round 20
// baseline (37.747 us; speedup 1.0000x reference)
//
#include <hip/hip_runtime.h>

#define N2 8192
#define NHALF 4096
#define DDIM 128
#define NCHUNK 16
#define CPC 512           // cols per chunk
#define NT 8              // B-tiles per chunk (512/64)
#define LN2F 0.69314718055994530942f
// SCALEF = sqrt(log2(e)/T) with T=0.5 -> sqrt(2.8853900817779268)
#define SCALEF 1.6986436f

typedef __attribute__((ext_vector_type(8))) short bf8_t;   // 8 bf16 = 4 VGPR
typedef __attribute__((ext_vector_type(4))) float f4_t;    // MFMA C/D frag

__device__ __forceinline__ float fexp2(float x) { return __builtin_amdgcn_exp2f(x); }
__device__ __forceinline__ float flog2(float x) { return __builtin_amdgcn_logf(x); }

__device__ __forceinline__ unsigned short f2bf(float f) {
  unsigned int x = __float_as_uint(f);
  x += 0x7fffu + ((x >> 16) & 1u);   // RNE (no NaN inputs here)
  return (unsigned short)(x >> 16);
}
__device__ __forceinline__ float bf2f(unsigned short h) {
  return __uint_as_float(((unsigned int)h) << 16);
}

// ---------------------------------------------------------------------------
// Kernel 1: normalize rows, scale by sqrt(log2e/T), store bf16 u[8192][128];
// also store dhat[i] = sum_k u_bf16[i][k]^2 (diag logit). Unchanged (passing).
// ---------------------------------------------------------------------------
__global__ __launch_bounds__(256) void knorm(const float* __restrict__ zi,
                                             const float* __restrict__ zj,
                                             unsigned short* __restrict__ u,
                                             float* __restrict__ dhat) {
  const int lane = threadIdx.x & 63;
  const int row = blockIdx.x * 4 + (threadIdx.x >> 6);
  const float* src = (row < NHALF) ? (zi + (size_t)row * DDIM)
                                   : (zj + (size_t)(row - NHALF) * DDIM);
  float2 x = *(const float2*)(src + lane * 2);
  float ss = x.x * x.x + x.y * x.y;
#pragma unroll
  for (int m = 32; m; m >>= 1) ss += __shfl_xor(ss, m);
  float scale = SCALEF / fmaxf(sqrtf(ss), 1e-8f);  // eps clamp as in reference
  unsigned short b0 = f2bf(x.x * scale);
  unsigned short b1 = f2bf(x.y * scale);
  *(unsigned int*)(u + (size_t)row * DDIM + lane * 2) =
      (unsigned int)b0 | ((unsigned int)b1 << 16);
  float f0 = bf2f(b0), f1 = bf2f(b1);
  float dd = f0 * f0 + f1 * f1;
#pragma unroll
  for (int m = 32; m; m >>= 1) dd += __shfl_xor(dd, m);
  if (lane == 0) dhat[row] = dd;
}

// ---------------------------------------------------------------------------
// Kernel 2: fused sim GEMM + per-row sum of exp2 (logits bounded, no max).
// r19 post-mortem: 1 WG/CU regressed ksim (no cross-WG overlap for prologue
// and barrier drains) -> revert to r18's best shape (256 rows x 512 cols,
// 8 waves of 64, grid 512 = 2 WG/CU). r20 structural change: TWO tiles per
// barrier period (T3/T4): 4-buf ring (64KB), prologue stages 4 tiles, each
// period = {vmcnt(4) -> s_barrier -> COMP(t) -> COMP(t+1) -> STAGE(t+2) ->
// STAGE(t+3)}. Barriers halve (8->4), compute phase doubles (~1600cy) so
// waves drift and mix pipes, DMA lead = one full period. WAR safety:
// buf[(t+2)%4] last read in period p-1, before this period's entry barrier.
// Staging mechanics validated r11-r19: lane-contiguous 1KB global_load_lds,
// involution pre-swizzle (16B-unit du of col c stored at du^(c&7)); swizzled
// ds_read applies the same XOR. A gathered once + pinned (lean a[2][4]).
// Lp layout [row][16] (chunk minor) for krow's 1-line partial read.
// ---------------------------------------------------------------------------
__global__ __launch_bounds__(512) void ksim(const unsigned short* __restrict__ u,
                                            float* __restrict__ Lp) {
  __shared__ short Bls[32768];  // 64 KB = 4 ring bufs x 16 KB
  const int tid = threadIdx.x;
  const int lane = tid & 63;
  const int w = tid >> 6;                  // 0..7
  const int rb = blockIdx.x >> 4;          // 0..31
  const int chunk = blockIdx.x & 15;       // 0..15
  const int lr = lane & 15, lq = lane >> 4;
  const int rowbase = rb * 256 + w * 32;   // wave's private 32 rows
  const int colbase = chunk * CPC;

  // ---- A: 32 rows per wave, gathered once from global, pinned (lean plan).
  bf8_t a[2][4];
#pragma unroll
  for (int s = 0; s < 2; s++)
#pragma unroll
    for (int kc = 0; kc < 4; kc++)
      a[s][kc] = *(const bf8_t*)(u + (size_t)(rowbase + s * 16 + lr) * DDIM +
                                 kc * 32 + lq * 8);
#pragma unroll
  for (int s = 0; s < 2; s++)
#pragma unroll
    for (int kc = 0; kc < 4; kc++)
      asm volatile("" : "+v"(a[s][kc]));   // forces drain of A loads

  f4_t L0 = {0.f, 0.f, 0.f, 0.f}, L1 = {0.f, 0.f, 0.f, 0.f};

  // ---- B stage: 64-col tile = 16KB = 16 linear 1KB DMAs (2 per wave).
  // LDS unit U holds global du = (U&15)^(col&7); DMA j (= w*2+i), lane l:
  // col_local = j*4+lq, src du = lr^(4*(j&1)+lq).
  auto STAGE = [&](int t) {
#pragma unroll
    for (int i = 0; i < 2; i++) {
      const int j = w * 2 + i;
      const int col_local = j * 4 + lq;
      const int sdu = lr ^ (4 * (j & 1) + lq);
      const unsigned short* src =
          u + (size_t)(colbase + t * 64 + col_local) * DDIM + sdu * 8;
      short* dst = &Bls[(t & 3) * 8192 + j * 512];
      __builtin_amdgcn_global_load_lds(
          (const __attribute__((address_space(1))) unsigned int*)src,
          (__attribute__((address_space(3))) unsigned int*)dst, 16, 0, 0);
    }
  };

  auto COMP = [&](int t) {
    const short* P = &Bls[(t & 3) * 8192];
#pragma unroll
    for (int g = 0; g < 4; g++) {
      bf8_t bv[4];
#pragma unroll
      for (int kc = 0; kc < 4; kc++)
        bv[kc] = *(const bf8_t*)&P[((g * 16 + lr) * 16 +
                                    ((kc * 4 + lq) ^ (lr & 7))) * 8];
      f4_t acc0 = {0.f, 0.f, 0.f, 0.f}, acc1 = {0.f, 0.f, 0.f, 0.f};
#pragma unroll
      for (int kc = 0; kc < 4; kc++) {
        acc0 = __builtin_amdgcn_mfma_f32_16x16x32_bf16(a[0][kc], bv[kc], acc0, 0, 0, 0);
        acc1 = __builtin_amdgcn_mfma_f32_16x16x32_bf16(a[1][kc], bv[kc], acc1, 0, 0, 0);
      }
#pragma unroll
      for (int r = 0; r < 4; r++) {
        L0[r] += fexp2(acc0[r]);
        L1[r] += fexp2(acc1[r]);
      }
    }
  };

  // prologue: 4 tiles in flight (8 DMAs/wave)
  STAGE(0); STAGE(1); STAGE(2); STAGE(3);
  // 4 periods of 2 tiles; counted vmcnt (4 = my next-period DMAs in flight)
#pragma unroll 1
  for (int t = 0; t < NT; t += 2) {
    if (t < NT - 2) {
      asm volatile("s_waitcnt vmcnt(4)" ::: "memory");   // tiles t,t+1 done
    } else {
      asm volatile("s_waitcnt vmcnt(0)" ::: "memory");
    }
    __builtin_amdgcn_sched_barrier(0);
    __builtin_amdgcn_s_barrier();                        // all waves ready
    __builtin_amdgcn_sched_barrier(0);
    COMP(t);
    COMP(t + 1);
    if (t + 2 < NT) STAGE(t + 2);
    if (t + 3 < NT) STAGE(t + 3);
  }

  // reduce across the 16 column-lanes; Lp layout [row][16] (chunk minor)
#pragma unroll
  for (int r = 0; r < 4; r++) {
    float v0 = L0[r], v1 = L1[r];
    v0 += __shfl_xor(v0, 1); v0 += __shfl_xor(v0, 2);
    v0 += __shfl_xor(v0, 4); v0 += __shfl_xor(v0, 8);
    v1 += __shfl_xor(v1, 1); v1 += __shfl_xor(v1, 2);
    v1 += __shfl_xor(v1, 4); v1 += __shfl_xor(v1, 8);
    if (lr == 0) {
      const int rrow = rowbase + lq * 4 + r;
      Lp[(size_t)rrow * NCHUNK + chunk] = v0;          // rows 0-15 of strip
      Lp[(size_t)(rrow + 16) * NCHUNK + chunk] = v1;   // rows 16-31
    }
  }
}

// ---------------------------------------------------------------------------
// Kernel 3: per-row loss, wave-per-row (validated r19): lane-parallel dot +
// shuffle reduce; Lp partials read as one 64B line. grid = 2048 x 256.
// ---------------------------------------------------------------------------
__global__ __launch_bounds__(256) void krow(const unsigned short* __restrict__ u,
                                            const float* __restrict__ dhat,
                                            const float* __restrict__ Lp,
                                            float* __restrict__ bsum) {
  const int lane = threadIdx.x & 63;
  const int w = threadIdx.x >> 6;
  const int i = blockIdx.x * 4 + w;
  const int j = (i + NHALF) & (N2 - 1);  // positive-pair label

  const unsigned int av = ((const unsigned int*)(u + (size_t)i * DDIM))[lane];
  const unsigned int bv = ((const unsigned int*)(u + (size_t)j * DDIM))[lane];
  float dot = __uint_as_float(av << 16) * __uint_as_float(bv << 16) +
              __uint_as_float(av & 0xffff0000u) * __uint_as_float(bv & 0xffff0000u);
  float ls = (lane < NCHUNK) ? Lp[(size_t)i * NCHUNK + lane] : 0.f;
#pragma unroll
  for (int m = 32; m; m >>= 1) {
    dot += __shfl_xor(dot, m);
    ls += __shfl_xor(ls, m);
  }
  __shared__ float sred[4];
  if (lane == 0) {
    const float L = ls - fexp2(dhat[i]);   // remove self-similarity term
    sred[w] = LN2F * (flog2(L) - dot);
  }
  __syncthreads();
  if (threadIdx.x == 0)
    bsum[blockIdx.x] = sred[0] + sred[1] + sred[2] + sred[3];
}

// ---------------------------------------------------------------------------
// Kernel 4: final mean over the 2048 block partials (fixed-order, determin.).
// ---------------------------------------------------------------------------
__global__ void kfinal(const float* __restrict__ bsum, float* __restrict__ out) {
  float v = 0.f;
#pragma unroll
  for (int jj = 0; jj < 32; jj++) v += bsum[threadIdx.x + 64 * jj];
#pragma unroll
  for (int m = 32; m; m >>= 1) v += __shfl_xor(v, m);
  if (threadIdx.x == 0) out[0] = v * (1.0f / N2);
}

// ---------------------------------------------------------------------------
// ws layout: u bf16 [8192][128] (2 MB) | dhat f32[8192] (32 KB) |
//            Lp f32[8192][16] (512 KB) | bsum f32[2048] (8 KB)  -> ~2.6 MB
// ---------------------------------------------------------------------------
extern "C" void kernel_launch(void* const* d_in, const int* in_sizes, int n_in,
                              void* d_out, int out_size, void* d_ws, size_t ws_size,
                              hipStream_t stream) {
  const float* zi = (const float*)d_in[0];
  const float* zj = (const float*)d_in[1];
  char* ws = (char*)d_ws;
  unsigned short* u = (unsigned short*)ws;
  float* dhat = (float*)(ws + (size_t)N2 * DDIM * 2);
  float* Lp = (float*)(ws + (size_t)N2 * DDIM * 2 + (size_t)N2 * 4);
  float* bsum = (float*)(ws + (size_t)N2 * DDIM * 2 + (size_t)N2 * 4 +
                         (size_t)NCHUNK * N2 * 4);
  float* out = (float*)d_out;

  hipLaunchKernelGGL(knorm, dim3(N2 / 4), dim3(256), 0, stream, zi, zj, u, dhat);
  hipLaunchKernelGGL(ksim, dim3((N2 / 256) * NCHUNK), dim3(512), 0, stream, u, Lp);
  hipLaunchKernelGGL(krow, dim3(N2 / 4), dim3(256), 0, stream, u, dhat, Lp, bsum);
  hipLaunchKernelGGL(kfinal, dim3(1), dim3(64), 0, stream, bsum, out);
}